// Round 4
// baseline (111.467 us; speedup 1.0000x reference)
//
#include <hip/hip_runtime.h>

// EatRxnLayer: h=0 (hunter), p=1 (prey), N=128, BATCH=4096.
// Output = [muTE (B,128) | ncovTE (B,128,128)] fp32, flat.
// ncovTE is zero except rows 0,1 and columns 0,1 (+4 corner cells).
// R1: hipMemsetAsync fill path (1.7 TB/s) was the bottleneck -> fused kernel.
// R2: 72 us; stores through L2. R3: nt stores -> 69.4 us (~4.9 TB/s mixed).
// R4: kill the latency serialization: no LDS, no barriers. Zero stores
//     (15/16 of traffic, zero data deps) issue immediately; the strided
//     float2 gather overlaps with them; per-batch scalars via wave-uniform
//     s_loads; rows 0/1 written as coalesced per-column scalar stores so
//     no transpose is needed.

#define NTOT 128

typedef float f4_t __attribute__((ext_vector_type(4)));
typedef float f2_t __attribute__((ext_vector_type(2)));

__global__ __launch_bounds__(256)
void eat_rxn_fused(const float* __restrict__ mu,
                   const float* __restrict__ ncov,
                   float* __restrict__ out_mu,
                   float* __restrict__ out_ncov) {
    const int b = blockIdx.x;
    const int t = threadIdx.x;

    const float* __restrict__ murow = mu   + (size_t)b * NTOT;
    const float* __restrict__ crow  = ncov + (size_t)b * NTOT * NTOT;
    float* __restrict__ omu = out_mu  + (size_t)b * NTOT;
    float* __restrict__ onc = out_ncov + (size_t)b * NTOT * NTOT;
    f4_t* __restrict__ onc4 = reinterpret_cast<f4_t*>(onc);

    // ---- issue the data-dependent loads FIRST so they fly during the zero pass
    float muj = 0.f;
    f2_t  cj  = {0.f, 0.f};
    float mh = 0.f, mp = 0.f, c00 = 0.f, c01 = 0.f, c10 = 0.f, c11 = 0.f;
    if (t < NTOT) {
        muj = __builtin_nontemporal_load(murow + t);
        cj  = __builtin_nontemporal_load(
                  reinterpret_cast<const f2_t*>(crow + (size_t)t * NTOT));
        // wave-uniform per-batch scalars -> scalar loads, no LDS broadcast
        mh = murow[0];  mp = murow[1];
        const f2_t c0 = *reinterpret_cast<const f2_t*>(crow);          // ncov[b,0,0:2]
        const f2_t c1 = *reinterpret_cast<const f2_t*>(crow + NTOT);   // ncov[b,1,0:2]
        c00 = c0.x; c01 = c0.y; c10 = c1.x; c11 = c1.y;
    }

    // ---- zero pass: no data dependencies, streams immediately.
    // Tile slots skipped: rows 0,1 (scalar-stored below) and c4==0 (col-pair
    // float4, data-stored below). Exactly-once coverage.
    const f4_t zero4 = {0.f, 0.f, 0.f, 0.f};
    #pragma unroll
    for (int i = 0; i < 16; ++i) {
        const int f  = i * 256 + t;   // float4 index in the 128x128 tile
        const int r  = f >> 5;        // row
        const int c4 = f & 31;        // float4 column
        if (r >= 2 && c4 != 0)
            __builtin_nontemporal_store(zero4, &onc4[f]);
    }
    if (t >= 1 && t < 32)
        __builtin_nontemporal_store(zero4, reinterpret_cast<f4_t*>(omu) + t);

    // ---- data stores (after the gather lands; no barrier needed)
    if (t < NTOT) {
        const float A  = -2.0f * mp * mh + c10;
        const float n3 = muj * A + mp * cj.x + mh * cj.y;

        const float n3_pph = -2.0f*mp*mp*mh + 2.0f*mp*c10 + mh*c11;
        const float n3_hhp = -2.0f*mh*mh*mp + 2.0f*mh*c01 + mp*c00;
        const float n3_hpp = -2.0f*mh*mp*mp + mh*c11 + 2.0f*mp*c01;
        const float vals_pp = -2.0f*n3_pph + c01;
        const float vals_hh =  2.0f*n3_hhp + c01;
        const float vals_hp = -n3_hhp + n3_hpp - c01;

        // rows 0 and 1, column t (coalesced scalar stores, full lines per wave)
        const float r0 = (t == 0) ? vals_hh : (t == 1) ? vals_hp :  n3;
        const float r1 = (t == 0) ? vals_hp : (t == 1) ? vals_pp : -n3;
        __builtin_nontemporal_store(r0, onc + t);
        __builtin_nontemporal_store(r1, onc + NTOT + t);

        // cols 0,1 (+ zero cols 2,3) for rows >= 2
        if (t >= 2)
            __builtin_nontemporal_store((f4_t){n3, -n3, 0.f, 0.f},
                                        &onc4[(size_t)t * 32]);

        // muTE: only two nonzeros
        if (t == 0)
            __builtin_nontemporal_store((f4_t){c01, -c01, 0.f, 0.f},
                                        reinterpret_cast<f4_t*>(omu));
    }
}

extern "C" void kernel_launch(void* const* d_in, const int* in_sizes, int n_in,
                              void* d_out, int out_size, void* d_ws, size_t ws_size,
                              hipStream_t stream) {
    const float* mu   = (const float*)d_in[0];
    const float* ncov = (const float*)d_in[1];

    const int batch = in_sizes[0] / NTOT;

    float* out_mu   = (float*)d_out;
    float* out_ncov = out_mu + (size_t)batch * NTOT;

    eat_rxn_fused<<<batch, 256, 0, stream>>>(mu, ncov, out_mu, out_ncov);
}

// Round 5
// 54.639 us; speedup vs baseline: 2.0401x; 2.0401x over previous
//
#include <hip/hip_runtime.h>

// EatRxnLayer: h=0 (hunter), p=1 (prey), N=128, BATCH=4096.
// Output = [muTE (B,128) | ncovTE (B,128,128)] fp32, flat.
// ncovTE is zero except rows 0,1 and columns 0,1 (+4 corner cells).
// R1: hipMemsetAsync fill (1.7 TB/s) was the bottleneck -> fused kernel.
// R2: 72 us. R3: nt stores -> 69.4 us. R4 FAILED (111 us): predicated zero
//     sweep created 16B holes -> partial-line nt writes. Lesson: streaming
//     stores must be full-width, unconditional, contiguous per instruction.
// R5: R3's exact store pattern (no holes) but NO LDS / NO barriers: thread
//     assignment chosen so every slot's value is thread-local.
//       lanes t<64      gather rows 4u..4u+3  -> rows 0/1 quads (i==0)
//       lanes t%32==0   gather rows {8i+k}    -> col0/1 pair quads (all i)
//       everyone else   stores pure zeros (no data deps, streams freely)

#define NTOT 128

typedef float f4_t __attribute__((ext_vector_type(4)));
typedef float f2_t __attribute__((ext_vector_type(2)));

__global__ __launch_bounds__(256)
void eat_rxn_fused(const float* __restrict__ mu,
                   const float* __restrict__ ncov,
                   float* __restrict__ out_mu,
                   float* __restrict__ out_ncov) {
    const int b = blockIdx.x;
    const int t = threadIdx.x;

    const float* __restrict__ murow = mu   + (size_t)b * NTOT;
    const float* __restrict__ crow  = ncov + (size_t)b * NTOT * NTOT;
    float* __restrict__ omu = out_mu  + (size_t)b * NTOT;
    float* __restrict__ onc = out_ncov + (size_t)b * NTOT * NTOT;
    f4_t* __restrict__ onc4 = reinterpret_cast<f4_t*>(onc);

    const int  k      = t >> 5;            // col-slot index for col lanes
    const bool isCol  = (t & 31) == 0;     // lanes owning the {n3,-n3,0,0} quad
    const bool isQuad = (t < 64);          // lanes owning rows 0/1 quads

    // block-uniform per-batch scalars -> scalar loads, no LDS broadcast
    const float mh  = murow[0], mp = murow[1];
    const f2_t  c0  = *reinterpret_cast<const f2_t*>(crow);         // ncov[b,0,0:2]
    const f2_t  c1  = *reinterpret_cast<const f2_t*>(crow + NTOT);  // ncov[b,1,0:2]
    const float c00 = c0.x, c01 = c0.y, c10 = c1.x, c11 = c1.y;
    const float A   = -2.0f * mp * mh + c10;

    // ---- gathers (plain cached loads; duplicate lines absorbed by L2) ----
    // col lanes: n3 for rows {8i+k}, i = 0..15
    float n3c[16];
    if (isCol) {
        #pragma unroll
        for (int i = 0; i < 16; ++i) {
            const int r = 8 * i + k;
            const f2_t c = *reinterpret_cast<const f2_t*>(crow + (size_t)r * NTOT);
            n3c[i] = murow[r] * A + mp * c.x + mh * c.y;
        }
    }
    // quad lanes: n3 for rows 4u..4u+3 (u = t & 31)
    float n3q[4];
    if (isQuad) {
        const int u = t & 31;
        const f4_t m4 = *reinterpret_cast<const f4_t*>(murow + 4 * u);
        #pragma unroll
        for (int q = 0; q < 4; ++q) {
            const f2_t c = *reinterpret_cast<const f2_t*>(crow + (size_t)(4 * u + q) * NTOT);
            n3q[q] = m4[q] * A + mp * c.x + mh * c.y;
        }
    }

    // corner cells (cheap; only lanes 0 and 32 consume)
    const float n3_pph = -2.0f*mp*mp*mh + 2.0f*mp*c10 + mh*c11;
    const float n3_hhp = -2.0f*mh*mh*mp + 2.0f*mh*c01 + mp*c00;
    const float n3_hpp = -2.0f*mh*mp*mp + mh*c11 + 2.0f*mp*c01;
    const float vals_pp = -2.0f*n3_pph + c01;
    const float vals_hh =  2.0f*n3_hhp + c01;
    const float vals_hp = -n3_hhp + n3_hpp - c01;

    // ---- sweep: 16 unconditional full-width float4 stores (no holes) ----
    #pragma unroll
    for (int i = 0; i < 16; ++i) {
        f4_t v = {0.f, 0.f, 0.f, 0.f};
        if (isCol)                 // rows >= 2 col pair (overridden below at i==0,t<64)
            v = (f4_t){n3c[i], -n3c[i], 0.f, 0.f};
        if (i == 0 && isQuad) {    // rows 0 and 1
            const float sgn = (t < 32) ? 1.0f : -1.0f;
            v = (f4_t){sgn * n3q[0], sgn * n3q[1], sgn * n3q[2], sgn * n3q[3]};
            if ((t & 31) == 0) {   // corner fixups: cols 0,1 of rows 0,1
                v.x = (t < 32) ? vals_hh : vals_hp;
                v.y = (t < 32) ? vals_hp : vals_pp;
            }
        }
        __builtin_nontemporal_store(v, &onc4[i * 256 + t]);
    }

    // muTE row: 32 float4s, only the first is nonzero
    if (t < 32) {
        f4_t v = {0.f, 0.f, 0.f, 0.f};
        if (t == 0) v = (f4_t){c01, -c01, 0.f, 0.f};
        __builtin_nontemporal_store(v, reinterpret_cast<f4_t*>(omu) + t);
    }
}

extern "C" void kernel_launch(void* const* d_in, const int* in_sizes, int n_in,
                              void* d_out, int out_size, void* d_ws, size_t ws_size,
                              hipStream_t stream) {
    const float* mu   = (const float*)d_in[0];
    const float* ncov = (const float*)d_in[1];

    const int batch = in_sizes[0] / NTOT;

    float* out_mu   = (float*)d_out;
    float* out_ncov = out_mu + (size_t)batch * NTOT;

    eat_rxn_fused<<<batch, 256, 0, stream>>>(mu, ncov, out_mu, out_ncov);
}